// Round 1
// baseline (377.365 us; speedup 1.0000x reference)
//
#include <hip/hip_runtime.h>

#define DT 0.01f

// ---------------- Pass 1: per-chunk local aggregate (zero initial state) ----
// B[c][n] = scan over chunk c rows with s=0 initial.
__global__ void fol_pass1(const float* __restrict__ in, const float* __restrict__ tau,
                          float* __restrict__ B, int N, int L) {
    const int chunk = blockIdx.y;
    const int N4 = N >> 2;
    const int ch4 = blockIdx.x * blockDim.x + threadIdx.x;
    if (ch4 >= N4) return;

    const float4 tv = reinterpret_cast<const float4*>(tau)[ch4];
    const float ax = DT / fmaxf(tv.x, DT), ay = DT / fmaxf(tv.y, DT),
                az = DT / fmaxf(tv.z, DT), aw = DT / fmaxf(tv.w, DT);
    const float qx = 1.f - ax, qy = 1.f - ay, qz = 1.f - az, qw = 1.f - aw;

    float sx = 0.f, sy = 0.f, sz = 0.f, sw = 0.f;
    const float4* p = reinterpret_cast<const float4*>(in) + (size_t)chunk * L * N4 + ch4;
    #pragma unroll 4
    for (int t = 0; t < L; ++t) {
        const float4 x = p[(size_t)t * N4];
        sx = fmaf(qx, sx, ax * x.x);
        sy = fmaf(qy, sy, ay * x.y);
        sz = fmaf(qz, sz, az * x.z);
        sw = fmaf(qw, sw, aw * x.w);
    }
    reinterpret_cast<float4*>(B)[(size_t)chunk * N4 + ch4] = make_float4(sx, sy, sz, sw);
}

// ---------------- Pass 2: sequential combine across chunks (per channel) ----
// In-place: B[c][n] (aggregate) -> S[c][n] (state entering chunk c).
// S_0 = input row 0 (reference: s_0 = input[0]).
__global__ void fol_pass2(const float* __restrict__ in, const float* __restrict__ tau,
                          float* __restrict__ B, int N, int C, int L) {
    const int ch = blockIdx.x * blockDim.x + threadIdx.x;
    if (ch >= N) return;
    const float a = DT / fmaxf(tau[ch], DT);
    const float q = 1.f - a;
    // qL = q^L by repeated squaring
    float qL = 1.f, b = q;
    int e = L;
    while (e) { if (e & 1) qL *= b; b *= b; e >>= 1; }

    float S = in[ch];  // row 0
    for (int c = 0; c < C; ++c) {
        const float Bc = B[(size_t)c * N + ch];
        B[(size_t)c * N + ch] = S;
        S = fmaf(qL, S, Bc);
    }
}

// ---------------- Pass 3: rescan each chunk from its true start state -------
__global__ void fol_pass3(const float* __restrict__ in, const float* __restrict__ tau,
                          const float* __restrict__ bias, const float* __restrict__ S,
                          float* __restrict__ out, int N, int L) {
    const int chunk = blockIdx.y;
    const int N4 = N >> 2;
    const int ch4 = blockIdx.x * blockDim.x + threadIdx.x;
    if (ch4 >= N4) return;

    const float4 tv = reinterpret_cast<const float4*>(tau)[ch4];
    const float4 bv = reinterpret_cast<const float4*>(bias)[ch4];
    const float ax = DT / fmaxf(tv.x, DT), ay = DT / fmaxf(tv.y, DT),
                az = DT / fmaxf(tv.z, DT), aw = DT / fmaxf(tv.w, DT);
    const float qx = 1.f - ax, qy = 1.f - ay, qz = 1.f - az, qw = 1.f - aw;

    const float4 sv = reinterpret_cast<const float4*>(S)[(size_t)chunk * N4 + ch4];
    float sx = sv.x, sy = sv.y, sz = sv.z, sw = sv.w;

    const float4* p = reinterpret_cast<const float4*>(in) + (size_t)chunk * L * N4 + ch4;
    float4*       o = reinterpret_cast<float4*>(out)      + (size_t)chunk * L * N4 + ch4;
    #pragma unroll 4
    for (int t = 0; t < L; ++t) {
        const float4 x = p[(size_t)t * N4];
        sx = fmaf(qx, sx, ax * x.x);
        sy = fmaf(qy, sy, ay * x.y);
        sz = fmaf(qz, sz, az * x.z);
        sw = fmaf(qw, sw, aw * x.w);
        o[(size_t)t * N4] = make_float4(sx + bv.x, sy + bv.y, sz + bv.z, sw + bv.w);
    }
}

// ---------------- Fallback: naive thread-per-channel scan -------------------
__global__ void fol_naive(const float* __restrict__ in, const float* __restrict__ tau,
                          const float* __restrict__ bias, float* __restrict__ out,
                          int N, int T) {
    const int ch = blockIdx.x * blockDim.x + threadIdx.x;
    if (ch >= N) return;
    const float a = DT / fmaxf(tau[ch], DT);
    const float q = 1.f - a;
    const float b = bias[ch];
    float s = in[ch];
    for (int t = 0; t < T; ++t) {
        const float x = in[(size_t)t * N + ch];
        s = fmaf(q, s, a * x);
        out[(size_t)t * N + ch] = s + b;
    }
}

extern "C" void kernel_launch(void* const* d_in, const int* in_sizes, int n_in,
                              void* d_out, int out_size, void* d_ws, size_t ws_size,
                              hipStream_t stream) {
    const float* in   = (const float*)d_in[0];
    const float* tau  = (const float*)d_in[1];
    const float* bias = (const float*)d_in[2];
    float* out = (float*)d_out;

    const int N = in_sizes[1];
    const int T = in_sizes[0] / N;

    // Pick chunk count C (power of two): largest <= 512 whose state array fits in ws.
    int C = 512;
    while (C > 1 && (((size_t)C * N * sizeof(float)) > ws_size || (T % C) != 0)) C >>= 1;

    const bool vec_ok = (N % 4 == 0);
    if (C < 2 || ((size_t)C * N * sizeof(float)) > ws_size || !vec_ok) {
        fol_naive<<<dim3((N + 255) / 256), dim3(256), 0, stream>>>(in, tau, bias, out, N, T);
        return;
    }

    const int L = T / C;
    float* B = (float*)d_ws;  // C x N floats, reused in-place as chunk start states
    const int N4 = N / 4;

    const dim3 blk(256);
    const dim3 g13((N4 + 255) / 256, C);
    fol_pass1<<<g13, blk, 0, stream>>>(in, tau, B, N, L);
    fol_pass2<<<dim3((N + 255) / 256), blk, 0, stream>>>(in, tau, B, N, C, L);
    fol_pass3<<<g13, blk, 0, stream>>>(in, tau, bias, B, out, N, L);
}

// Round 7
// 271.606 us; speedup vs baseline: 1.3894x; 1.3894x over previous
//
#include <hip/hip_runtime.h>

#define DT 0.01f

// Native 4-float vector for nontemporal builtins (HIP's float4 is a class
// type, which __builtin_nontemporal_store rejects).
typedef float f32x4 __attribute__((ext_vector_type(4)));

// ================= Specialized path: T % 512 == 0, L = T/512 == 16 =========

// ---- Pass 1 (L=16): per-chunk local aggregate, zero initial state ----------
__global__ __launch_bounds__(256) void fol_pass1_L16(
        const float* __restrict__ in, const float* __restrict__ tau,
        float* __restrict__ B, int N4) {
    const int chunk = blockIdx.y;
    const int ch4 = blockIdx.x * 256 + threadIdx.x;
    if (ch4 >= N4) return;

    // Issue ALL 16 row loads up front -> 16 loads in flight per thread.
    const float4* p = reinterpret_cast<const float4*>(in) + (size_t)chunk * 16 * N4 + ch4;
    float4 x[16];
    #pragma unroll
    for (int t = 0; t < 16; ++t) x[t] = p[(size_t)t * N4];

    const float4 tv = reinterpret_cast<const float4*>(tau)[ch4];
    const float ax = DT / fmaxf(tv.x, DT), ay = DT / fmaxf(tv.y, DT),
                az = DT / fmaxf(tv.z, DT), aw = DT / fmaxf(tv.w, DT);
    const float qx = 1.f - ax, qy = 1.f - ay, qz = 1.f - az, qw = 1.f - aw;

    float sx = 0.f, sy = 0.f, sz = 0.f, sw = 0.f;
    #pragma unroll
    for (int t = 0; t < 16; ++t) {
        sx = fmaf(qx, sx, ax * x[t].x);
        sy = fmaf(qy, sy, ay * x[t].y);
        sz = fmaf(qz, sz, az * x[t].z);
        sw = fmaf(qw, sw, aw * x[t].w);
    }
    reinterpret_cast<float4*>(B)[(size_t)chunk * N4 + ch4] = make_float4(sx, sy, sz, sw);
}

// ---- Pass 2: sequential combine across chunks, software-pipelined ----------
// In-place B[c][n] (aggregate) -> S[c][n] (state entering chunk c).
// Requires C % 32 == 0. Loads for batch k+1 are issued before the FMA chain
// of batch k consumes batch k (all loads are independent of S).
__global__ __launch_bounds__(256) void fol_pass2_pipe(
        const float* __restrict__ in, const float* __restrict__ tau,
        float* __restrict__ B, int N, int C, int L) {
    const int ch = blockIdx.x * 256 + threadIdx.x;
    if (ch >= N) return;
    const float a = DT / fmaxf(tau[ch], DT);
    const float q = 1.f - a;
    float qL = 1.f, b = q;
    int e = L;
    while (e) { if (e & 1) qL *= b; b *= b; e >>= 1; }

    float S = in[ch];  // s_0 = input[0]

    constexpr int BATCH = 32;
    float x[BATCH], xn[BATCH];
    #pragma unroll
    for (int j = 0; j < BATCH; ++j) x[j] = B[(size_t)j * N + ch];

    for (int cb = 0; cb < C; cb += BATCH) {
        const int nb = cb + BATCH;
        if (nb < C) {
            #pragma unroll
            for (int j = 0; j < BATCH; ++j) xn[j] = B[(size_t)(nb + j) * N + ch];
        }
        #pragma unroll
        for (int j = 0; j < BATCH; ++j) {
            B[(size_t)(cb + j) * N + ch] = S;     // publish start state of chunk cb+j
            S = fmaf(qL, S, x[j]);                // advance by one chunk
        }
        #pragma unroll
        for (int j = 0; j < BATCH; ++j) x[j] = xn[j];
    }
}

// ---- Pass 3 (L=16): rescan each chunk from its true start state ------------
__global__ __launch_bounds__(256) void fol_pass3_L16(
        const float* __restrict__ in, const float* __restrict__ tau,
        const float* __restrict__ bias, const float* __restrict__ S,
        float* __restrict__ out, int N4) {
    const int chunk = blockIdx.y;
    const int ch4 = blockIdx.x * 256 + threadIdx.x;
    if (ch4 >= N4) return;

    const float4* p = reinterpret_cast<const float4*>(in) + (size_t)chunk * 16 * N4 + ch4;
    float4 x[16];
    #pragma unroll
    for (int t = 0; t < 16; ++t) x[t] = p[(size_t)t * N4];

    const float4 tv = reinterpret_cast<const float4*>(tau)[ch4];
    const float4 bv = reinterpret_cast<const float4*>(bias)[ch4];
    const float ax = DT / fmaxf(tv.x, DT), ay = DT / fmaxf(tv.y, DT),
                az = DT / fmaxf(tv.z, DT), aw = DT / fmaxf(tv.w, DT);
    const float qx = 1.f - ax, qy = 1.f - ay, qz = 1.f - az, qw = 1.f - aw;

    const float4 sv = reinterpret_cast<const float4*>(S)[(size_t)chunk * N4 + ch4];
    float sx = sv.x, sy = sv.y, sz = sv.z, sw = sv.w;

    f32x4* o = reinterpret_cast<f32x4*>(out) + (size_t)chunk * 16 * N4 + ch4;
    #pragma unroll
    for (int t = 0; t < 16; ++t) {
        sx = fmaf(qx, sx, ax * x[t].x);
        sy = fmaf(qy, sy, ay * x[t].y);
        sz = fmaf(qz, sz, az * x[t].z);
        sw = fmaf(qw, sw, aw * x[t].w);
        // Nontemporal: don't let the output stream evict the (re-read) input
        // from L2/L3.
        f32x4 ov; ov.x = sx + bv.x; ov.y = sy + bv.y; ov.z = sz + bv.z; ov.w = sw + bv.w;
        __builtin_nontemporal_store(ov, &o[(size_t)t * N4]);
    }
}

// ================= Generic fallback path ====================================

__global__ void fol_pass1_gen(const float* __restrict__ in, const float* __restrict__ tau,
                              float* __restrict__ B, int N, int L) {
    const int chunk = blockIdx.y;
    const int N4 = N >> 2;
    const int ch4 = blockIdx.x * blockDim.x + threadIdx.x;
    if (ch4 >= N4) return;
    const float4 tv = reinterpret_cast<const float4*>(tau)[ch4];
    const float ax = DT / fmaxf(tv.x, DT), ay = DT / fmaxf(tv.y, DT),
                az = DT / fmaxf(tv.z, DT), aw = DT / fmaxf(tv.w, DT);
    const float qx = 1.f - ax, qy = 1.f - ay, qz = 1.f - az, qw = 1.f - aw;
    float sx = 0.f, sy = 0.f, sz = 0.f, sw = 0.f;
    const float4* p = reinterpret_cast<const float4*>(in) + (size_t)chunk * L * N4 + ch4;
    #pragma unroll 8
    for (int t = 0; t < L; ++t) {
        const float4 x = p[(size_t)t * N4];
        sx = fmaf(qx, sx, ax * x.x);
        sy = fmaf(qy, sy, ay * x.y);
        sz = fmaf(qz, sz, az * x.z);
        sw = fmaf(qw, sw, aw * x.w);
    }
    reinterpret_cast<float4*>(B)[(size_t)chunk * N4 + ch4] = make_float4(sx, sy, sz, sw);
}

__global__ void fol_pass3_gen(const float* __restrict__ in, const float* __restrict__ tau,
                              const float* __restrict__ bias, const float* __restrict__ S,
                              float* __restrict__ out, int N, int L) {
    const int chunk = blockIdx.y;
    const int N4 = N >> 2;
    const int ch4 = blockIdx.x * blockDim.x + threadIdx.x;
    if (ch4 >= N4) return;
    const float4 tv = reinterpret_cast<const float4*>(tau)[ch4];
    const float4 bv = reinterpret_cast<const float4*>(bias)[ch4];
    const float ax = DT / fmaxf(tv.x, DT), ay = DT / fmaxf(tv.y, DT),
                az = DT / fmaxf(tv.z, DT), aw = DT / fmaxf(tv.w, DT);
    const float qx = 1.f - ax, qy = 1.f - ay, qz = 1.f - az, qw = 1.f - aw;
    const float4 sv = reinterpret_cast<const float4*>(S)[(size_t)chunk * N4 + ch4];
    float sx = sv.x, sy = sv.y, sz = sv.z, sw = sv.w;
    const float4* p = reinterpret_cast<const float4*>(in) + (size_t)chunk * L * N4 + ch4;
    float4*       o = reinterpret_cast<float4*>(out)      + (size_t)chunk * L * N4 + ch4;
    #pragma unroll 8
    for (int t = 0; t < L; ++t) {
        const float4 x = p[(size_t)t * N4];
        sx = fmaf(qx, sx, ax * x.x);
        sy = fmaf(qy, sy, ay * x.y);
        sz = fmaf(qz, sz, az * x.z);
        sw = fmaf(qw, sw, aw * x.w);
        o[(size_t)t * N4] = make_float4(sx + bv.x, sy + bv.y, sz + bv.z, sw + bv.w);
    }
}

__global__ void fol_naive(const float* __restrict__ in, const float* __restrict__ tau,
                          const float* __restrict__ bias, float* __restrict__ out,
                          int N, int T) {
    const int ch = blockIdx.x * blockDim.x + threadIdx.x;
    if (ch >= N) return;
    const float a = DT / fmaxf(tau[ch], DT);
    const float q = 1.f - a;
    const float b = bias[ch];
    float s = in[ch];
    for (int t = 0; t < T; ++t) {
        const float x = in[(size_t)t * N + ch];
        s = fmaf(q, s, a * x);
        out[(size_t)t * N + ch] = s + b;
    }
}

extern "C" void kernel_launch(void* const* d_in, const int* in_sizes, int n_in,
                              void* d_out, int out_size, void* d_ws, size_t ws_size,
                              hipStream_t stream) {
    const float* in   = (const float*)d_in[0];
    const float* tau  = (const float*)d_in[1];
    const float* bias = (const float*)d_in[2];
    float* out = (float*)d_out;

    const int N = in_sizes[1];
    const int T = in_sizes[0] / N;

    const bool vec_ok = (N % 4 == 0);
    float* B = (float*)d_ws;

    // Specialized fast path: C=512 chunks of L=16 (T=8192), ws holds C*N floats.
    if (vec_ok && T == 8192 && ((size_t)512 * N * sizeof(float)) <= ws_size) {
        const int C = 512, L = 16, N4 = N / 4;
        const dim3 blk(256);
        const dim3 g13((N4 + 255) / 256, C);
        fol_pass1_L16<<<g13, blk, 0, stream>>>(in, tau, B, N4);
        fol_pass2_pipe<<<dim3((N + 255) / 256), blk, 0, stream>>>(in, tau, B, N, C, L);
        fol_pass3_L16<<<g13, blk, 0, stream>>>(in, tau, bias, B, out, N4);
        return;
    }

    // Generic chunked path.
    int C = 512;
    while (C > 1 && (((size_t)C * N * sizeof(float)) > ws_size || (T % C) != 0 || (C % 32) != 0)) C >>= 1;
    if (C >= 32 && vec_ok && ((size_t)C * N * sizeof(float)) <= ws_size) {
        const int L = T / C, N4 = N / 4;
        const dim3 blk(256);
        const dim3 g13((N4 + 255) / 256, C);
        fol_pass1_gen<<<g13, blk, 0, stream>>>(in, tau, B, N, L);
        fol_pass2_pipe<<<dim3((N + 255) / 256), blk, 0, stream>>>(in, tau, B, N, C, L);
        fol_pass3_gen<<<g13, blk, 0, stream>>>(in, tau, bias, B, out, N, L);
        return;
    }

    fol_naive<<<dim3((N + 255) / 256), dim3(256), 0, stream>>>(in, tau, bias, out, N, T);
}